// Round 2
// baseline (1903.288 us; speedup 1.0000x reference)
//
#include <hip/hip_runtime.h>
#include <cstdint>
#include <cstdio>

#define DM 1024
#define HM 4096
#define NE 7
#define NTOK 8192
#define ROWS_R 16384   // 2*NTOK routed rows
#define ROWS_T 24576   // + NTOK shared rows

typedef __bf16 bf16;
typedef __bf16 bf16x8 __attribute__((ext_vector_type(8)));
typedef __bf16 bf16x4 __attribute__((ext_vector_type(4)));
typedef float f32x4 __attribute__((ext_vector_type(4)));
typedef unsigned int u32;

__device__ __forceinline__ void gload_lds16(const bf16* g, bf16* l) {
  __builtin_amdgcn_global_load_lds((const __attribute__((address_space(1))) u32*)g,
                                   (__attribute__((address_space(3))) u32*)l, 16, 0, 0);
}

// ---------------- fp32 -> bf16 straight convert (x) ----------------
__global__ void cvt_bf16_kernel(const float* __restrict__ in, bf16* __restrict__ out, int n) {
  int i = (blockIdx.x * 256 + threadIdx.x) * 4;
  if (i >= n) return;
  float4 v = *(const float4*)(in + i);
  bf16x4 o; o[0] = (bf16)v.x; o[1] = (bf16)v.y; o[2] = (bf16)v.z; o[3] = (bf16)v.w;
  *(bf16x4*)(out + i) = o;
}

// ---------------- fp32 [R][C] -> bf16 [C][R] tiled transpose ----------------
__global__ void transpose_cvt_kernel(const float* __restrict__ in, bf16* __restrict__ out,
                                     int R, int C) {
  __shared__ float tile[32][33];
  const float* ib = in + (size_t)blockIdx.z * R * C;
  bf16* ob = out + (size_t)blockIdx.z * R * C;
  int c0 = blockIdx.x * 32, r0 = blockIdx.y * 32;
  int tx = threadIdx.x, ty = threadIdx.y;   // 32 x 8
  #pragma unroll
  for (int i = 0; i < 32; i += 8)
    tile[ty + i][tx] = ib[(size_t)(r0 + ty + i) * C + c0 + tx];
  __syncthreads();
  #pragma unroll
  for (int i = 0; i < 32; i += 8)
    ob[(size_t)(c0 + ty + i) * R + r0 + tx] = (bf16)tile[tx][ty + i];
}

// ---------------- router: logits, top-2, softmax, counts ----------------
__global__ __launch_bounds__(256) void router_kernel(
    const float* __restrict__ x, const float* __restrict__ rw,
    int* __restrict__ t_idx, float* __restrict__ t_w, int* __restrict__ counts) {
  int wave = threadIdx.x >> 6, lane = threadIdx.x & 63;
  int t = blockIdx.x * 4 + wave;
  float acc[NE];
  #pragma unroll
  for (int e = 0; e < NE; e++) acc[e] = 0.f;
  const float* xr = x + (size_t)t * DM;
  for (int i = lane; i < DM; i += 64) {
    float xv = xr[i];
    #pragma unroll
    for (int e = 0; e < NE; e++) acc[e] += xv * rw[e * DM + i];
  }
  #pragma unroll
  for (int e = 0; e < NE; e++) {
    float v = acc[e];
    #pragma unroll
    for (int s = 32; s > 0; s >>= 1) v += __shfl_xor(v, s, 64);
    acc[e] = v;
  }
  if (lane == 0) {
    int b0 = 0; float v0 = acc[0];
    #pragma unroll
    for (int e = 1; e < NE; e++) if (acc[e] > v0) { v0 = acc[e]; b0 = e; }
    int b1 = -1; float v1 = -3.0e38f;
    #pragma unroll
    for (int e = 0; e < NE; e++) if (e != b0 && acc[e] > v1) { v1 = acc[e]; b1 = e; }
    float p0 = 1.f / (1.f + __expf(v1 - v0));  // softmax over top-2 (v0 >= v1)
    t_idx[t * 2] = b0; t_idx[t * 2 + 1] = b1;
    t_w[t * 2] = p0;  t_w[t * 2 + 1] = 1.f - p0;
    atomicAdd(&counts[b0], 1); atomicAdd(&counts[b1], 1);
  }
}

// ---------------- prefix: segment offsets ----------------
__global__ void prefix_kernel(const int* __restrict__ counts, int* __restrict__ segs) {
  if (threadIdx.x == 0) {
    int o = 0;
    for (int e = 0; e < NE; e++) { segs[e] = o; segs[8 + e] = counts[e]; o += counts[e]; }
    segs[7] = ROWS_R;   // shared expert segment
    segs[15] = NTOK;
  }
}

// ---------------- fill per-expert row lists ----------------
__global__ void fill_kernel(const int* __restrict__ t_idx, int* __restrict__ cursor,
                            const int* __restrict__ segs, int* __restrict__ tok_of_row,
                            int* __restrict__ row_of) {
  int t = blockIdx.x * 256 + threadIdx.x;
  #pragma unroll
  for (int s = 0; s < 2; s++) {
    int e = t_idx[t * 2 + s];
    int pos = atomicAdd(&cursor[e], 1);
    int r = segs[e] + pos;
    tok_of_row[r] = t;
    row_of[t * 2 + s] = r;
  }
  tok_of_row[ROWS_R + t] = t;  // shared segment: identity
}

// ---------------- GEMM1: h = silu(x@Wg) * (x@Wu), gathered rows ----------------
// BM=128 BN=64 BK=32; 4 waves, each 64rows x 32cols per matrix; two B matrices fused.
// e_fixed >= 0: expert index fixed (gridDim.z == 1). compact: weight base has no
// per-expert stride and hb is indexed from row 0 (per-expert slot reuse).
__global__ __launch_bounds__(256, 2) void gemm1_kernel(
    const bf16* __restrict__ xb, const bf16* __restrict__ wgT, const bf16* __restrict__ wuT,
    const bf16* __restrict__ swgT, const bf16* __restrict__ swuT,
    const int* __restrict__ segs, const int* __restrict__ tok_of_row,
    bf16* __restrict__ hb, int e_fixed, int compact) {
  const int e = (e_fixed >= 0) ? e_fixed : (int)blockIdx.z;
  const int off = segs[e], cnt = segs[8 + e];
  const int hoff = compact ? 0 : off;
  const int r0 = blockIdx.y * 128;
  if (r0 >= cnt) return;
  const int n0 = blockIdx.x * 64;
  const size_t estride = compact ? 0 : (size_t)e * HM * DM;
  const bf16* bg = (e < NE) ? wgT + estride : swgT;
  const bf16* bu = (e < NE) ? wuT + estride : swuT;

  __shared__ __align__(16) bf16 As[128 * 32];
  __shared__ __align__(16) bf16 Bgs[64 * 32];
  __shared__ __align__(16) bf16 Bus[64 * 32];

  const int tid = threadIdx.x, wave = tid >> 6, lane = tid & 63;
  int lr0 = wave * 16 + (lane >> 2);
  int lr1 = lr0 + 64;
  int i0 = min(r0 + lr0, cnt - 1);
  int i1 = min(r0 + lr1, cnt - 1);
  const bf16* agp0 = xb + (size_t)tok_of_row[off + i0] * DM + (lane & 3) * 8;
  const bf16* agp1 = xb + (size_t)tok_of_row[off + i1] * DM + (lane & 3) * 8;
  const bf16* bgp = bg + (size_t)(n0 + lr0) * DM + (lane & 3) * 8;
  const bf16* bup = bu + (size_t)(n0 + lr0) * DM + (lane & 3) * 8;
  bf16* As_w0 = &As[wave * 512];
  bf16* As_w1 = &As[(4 + wave) * 512];
  bf16* Bgs_w = &Bgs[wave * 512];
  bf16* Bus_w = &Bus[wave * 512];

  const int wr = wave & 1, wc = wave >> 1;
  const int mbase = wr * 64, nbase = wc * 32;
  const int fl = lane & 15, fq = lane >> 4;
  f32x4 accg[4][2] = {}; f32x4 accu[4][2] = {};

  for (int k0 = 0; k0 < DM; k0 += 32) {
    gload_lds16(agp0 + k0, As_w0);
    gload_lds16(agp1 + k0, As_w1);
    gload_lds16(bgp + k0, Bgs_w);
    gload_lds16(bup + k0, Bus_w);
    __syncthreads();
    bf16x8 af[4], bgf[2], buf[2];
    #pragma unroll
    for (int i = 0; i < 4; i++)
      af[i] = *(const bf16x8*)&As[(mbase + i * 16 + fl) * 32 + fq * 8];
    #pragma unroll
    for (int j = 0; j < 2; j++) {
      bgf[j] = *(const bf16x8*)&Bgs[(nbase + j * 16 + fl) * 32 + fq * 8];
      buf[j] = *(const bf16x8*)&Bus[(nbase + j * 16 + fl) * 32 + fq * 8];
    }
    #pragma unroll
    for (int i = 0; i < 4; i++)
      #pragma unroll
      for (int j = 0; j < 2; j++) {
        accg[i][j] = __builtin_amdgcn_mfma_f32_16x16x32_bf16(af[i], bgf[j], accg[i][j], 0, 0, 0);
        accu[i][j] = __builtin_amdgcn_mfma_f32_16x16x32_bf16(af[i], buf[j], accu[i][j], 0, 0, 0);
      }
    __syncthreads();
  }
  #pragma unroll
  for (int i = 0; i < 4; i++)
    #pragma unroll
    for (int j = 0; j < 2; j++)
      #pragma unroll
      for (int r = 0; r < 4; r++) {
        int lr = mbase + i * 16 + fq * 4 + r;
        if (r0 + lr < cnt) {
          float g = accg[i][j][r], u = accu[i][j][r];
          float s = g / (1.f + __expf(-g));
          int col = n0 + nbase + j * 16 + fl;
          hb[(size_t)(hoff + r0 + lr) * HM + col] = (bf16)(s * u);
        }
      }
}

// ---------------- GEMM2: y = h @ Wd, compact rows ----------------
// BM=128 BN=128 BK=32; 4 waves each 64x64.
__global__ __launch_bounds__(256, 2) void gemm2_kernel(
    const bf16* __restrict__ hb, const bf16* __restrict__ wdT, const bf16* __restrict__ swdT,
    const int* __restrict__ segs, bf16* __restrict__ yb, int e_fixed, int compact) {
  const int e = (e_fixed >= 0) ? e_fixed : (int)blockIdx.z;
  const int off = segs[e], cnt = segs[8 + e];
  const int hoff = compact ? 0 : off;
  const int r0 = blockIdx.y * 128;
  if (r0 >= cnt) return;
  const int n0 = blockIdx.x * 128;
  const size_t estride = compact ? 0 : (size_t)e * DM * HM;
  const bf16* bd = (e < NE) ? wdT + estride : swdT;

  __shared__ __align__(16) bf16 As[128 * 32];
  __shared__ __align__(16) bf16 Bs[128 * 32];

  const int tid = threadIdx.x, wave = tid >> 6, lane = tid & 63;
  int lr0 = wave * 16 + (lane >> 2);
  int lr1 = lr0 + 64;
  int i0 = min(r0 + lr0, cnt - 1);
  int i1 = min(r0 + lr1, cnt - 1);
  const bf16* agp0 = hb + (size_t)(hoff + i0) * HM + (lane & 3) * 8;
  const bf16* agp1 = hb + (size_t)(hoff + i1) * HM + (lane & 3) * 8;
  const bf16* bgp0 = bd + (size_t)(n0 + lr0) * HM + (lane & 3) * 8;
  const bf16* bgp1 = bgp0 + (size_t)64 * HM;
  bf16* As_w0 = &As[wave * 512];
  bf16* As_w1 = &As[(4 + wave) * 512];
  bf16* Bs_w0 = &Bs[wave * 512];
  bf16* Bs_w1 = &Bs[(4 + wave) * 512];

  const int wr = wave & 1, wc = wave >> 1;
  const int mbase = wr * 64, nbase = wc * 64;
  const int fl = lane & 15, fq = lane >> 4;
  f32x4 acc[4][4] = {};

  for (int k0 = 0; k0 < HM; k0 += 32) {
    gload_lds16(agp0 + k0, As_w0);
    gload_lds16(agp1 + k0, As_w1);
    gload_lds16(bgp0 + k0, Bs_w0);
    gload_lds16(bgp1 + k0, Bs_w1);
    __syncthreads();
    bf16x8 af[4], bf[4];
    #pragma unroll
    for (int i = 0; i < 4; i++) {
      af[i] = *(const bf16x8*)&As[(mbase + i * 16 + fl) * 32 + fq * 8];
      bf[i] = *(const bf16x8*)&Bs[(nbase + i * 16 + fl) * 32 + fq * 8];
    }
    #pragma unroll
    for (int i = 0; i < 4; i++)
      #pragma unroll
      for (int j = 0; j < 4; j++)
        acc[i][j] = __builtin_amdgcn_mfma_f32_16x16x32_bf16(af[i], bf[j], acc[i][j], 0, 0, 0);
    __syncthreads();
  }
  #pragma unroll
  for (int i = 0; i < 4; i++)
    #pragma unroll
    for (int j = 0; j < 4; j++)
      #pragma unroll
      for (int r = 0; r < 4; r++) {
        int lr = mbase + i * 16 + fq * 4 + r;
        if (r0 + lr < cnt) {
          int col = n0 + nbase + j * 16 + fl;
          yb[(size_t)(off + r0 + lr) * DM + col] = (bf16)acc[i][j][r];
        }
      }
}

// ---------------- combine: out = w0*y[r0] + w1*y[r1] + y[shared] ----------------
__global__ __launch_bounds__(256) void combine_kernel(
    const bf16* __restrict__ yb, const int* __restrict__ row_of,
    const float* __restrict__ t_w, float* __restrict__ out) {
  int t = blockIdx.x;
  int d = threadIdx.x * 4;
  int r0 = row_of[t * 2], r1 = row_of[t * 2 + 1];
  float w0 = t_w[t * 2], w1 = t_w[t * 2 + 1];
  bf16x4 a = *(const bf16x4*)&yb[(size_t)r0 * DM + d];
  bf16x4 b = *(const bf16x4*)&yb[(size_t)r1 * DM + d];
  bf16x4 c = *(const bf16x4*)&yb[(size_t)(ROWS_R + t) * DM + d];
  float4 o;
  o.x = w0 * (float)a[0] + w1 * (float)b[0] + (float)c[0];
  o.y = w0 * (float)a[1] + w1 * (float)b[1] + (float)c[1];
  o.z = w0 * (float)a[2] + w1 * (float)b[2] + (float)c[2];
  o.w = w0 * (float)a[3] + w1 * (float)b[3] + (float)c[3];
  *(float4*)&out[(size_t)t * DM + d] = o;
}

extern "C" void kernel_launch(void* const* d_in, const int* in_sizes, int n_in,
                              void* d_out, int out_size, void* d_ws, size_t ws_size,
                              hipStream_t stream) {
  const float* x        = (const float*)d_in[0];
  const float* router_w = (const float*)d_in[1];
  const float* w_gate   = (const float*)d_in[2];
  const float* w_up     = (const float*)d_in[3];
  const float* w_down   = (const float*)d_in[4];
  const float* sw_gate  = (const float*)d_in[5];
  const float* sw_up    = (const float*)d_in[6];
  const float* sw_down  = (const float*)d_in[7];
  float* out = (float*)d_out;

  const size_t WEXP = (size_t)HM * DM;           // elements per expert weight matrix
  // tier-1 needs ~470 MB; tier-2 needs ~160 MB
  const size_t NEED_T1 = (size_t)NTOK * DM * 2 + 7 * WEXP * 2 * 3 + 3 * WEXP * 2 +
                         (size_t)ROWS_T * HM * 2 + (size_t)ROWS_T * DM * 2 + (1 << 20);
  const bool tier1 = ws_size >= NEED_T1 + (16 << 20);

  char* p = (char*)d_ws;
  auto alloc = [&](size_t bytes) { char* r = p; p += (bytes + 255) & ~(size_t)255; return r; };

  bf16* xb = (bf16*)alloc((size_t)NTOK * DM * 2);
  bf16 *wgT, *wuT, *wdT, *swgT, *swuT, *swdT, *hb, *yb;
  if (tier1) {
    wgT  = (bf16*)alloc(7 * WEXP * 2);
    wuT  = (bf16*)alloc(7 * WEXP * 2);
    wdT  = (bf16*)alloc(7 * WEXP * 2);
    swgT = (bf16*)alloc(WEXP * 2);
    swuT = (bf16*)alloc(WEXP * 2);
    swdT = (bf16*)alloc(WEXP * 2);
    hb   = (bf16*)alloc((size_t)ROWS_T * HM * 2);   // full: all experts + shared
  } else {
    wgT  = (bf16*)alloc(WEXP * 2);   // single-expert slots, reused
    wuT  = (bf16*)alloc(WEXP * 2);
    wdT  = (bf16*)alloc(WEXP * 2);
    swgT = wgT; swuT = wuT; swdT = wdT;
    hb   = (bf16*)alloc((size_t)NTOK * HM * 2);     // one expert (worst case all tokens)
  }
  yb = (bf16*)alloc((size_t)ROWS_T * DM * 2);
  int* counts     = (int*)alloc(8 * 4);
  int* cursor     = (int*)alloc(8 * 4);
  int* segs       = (int*)alloc(16 * 4);
  int* t_idx      = (int*)alloc((size_t)NTOK * 2 * 4);
  int* row_of     = (int*)alloc((size_t)NTOK * 2 * 4);
  int* tok_of_row = (int*)alloc((size_t)ROWS_T * 4);
  float* t_w      = (float*)alloc((size_t)NTOK * 2 * 4);
  if ((size_t)(p - (char*)d_ws) > ws_size) {
    fprintf(stderr, "MoE kernel: ws too small: need %zu have %zu (tier1=%d)\n",
            (size_t)(p - (char*)d_ws), ws_size, (int)tier1);
    return;  // refuse to launch OOB — fails validation instead of crashing
  }

  hipMemsetAsync(counts, 0, 8 * 4, stream);
  hipMemsetAsync(cursor, 0, 8 * 4, stream);

  cvt_bf16_kernel<<<(NTOK * DM) / 1024, 256, 0, stream>>>(x, xb, NTOK * DM);
  router_kernel<<<NTOK / 4, 256, 0, stream>>>(x, router_w, t_idx, t_w, counts);
  prefix_kernel<<<1, 64, 0, stream>>>(counts, segs);
  fill_kernel<<<NTOK / 256, 256, 0, stream>>>(t_idx, cursor, segs, tok_of_row, row_of);

  const dim3 tb(32, 8);
  const dim3 tg_gu(HM / 32, DM / 32, 1);   // gate/up: [DM][HM] -> [HM][DM]
  const dim3 tg_d(DM / 32, HM / 32, 1);    // down:    [HM][DM] -> [DM][HM]

  if (tier1) {
    transpose_cvt_kernel<<<dim3(HM / 32, DM / 32, NE), tb, 0, stream>>>(w_gate, wgT, DM, HM);
    transpose_cvt_kernel<<<dim3(HM / 32, DM / 32, NE), tb, 0, stream>>>(w_up, wuT, DM, HM);
    transpose_cvt_kernel<<<dim3(DM / 32, HM / 32, NE), tb, 0, stream>>>(w_down, wdT, HM, DM);
    transpose_cvt_kernel<<<tg_gu, tb, 0, stream>>>(sw_gate, swgT, DM, HM);
    transpose_cvt_kernel<<<tg_gu, tb, 0, stream>>>(sw_up, swuT, DM, HM);
    transpose_cvt_kernel<<<tg_d, tb, 0, stream>>>(sw_down, swdT, HM, DM);
    gemm1_kernel<<<dim3(HM / 64, 64, 8), 256, 0, stream>>>(
        xb, wgT, wuT, swgT, swuT, segs, tok_of_row, hb, -1, 0);
    gemm2_kernel<<<dim3(DM / 128, 64, 8), 256, 0, stream>>>(
        hb, wdT, swdT, segs, yb, -1, 0);
  } else {
    // shared expert first (uses the weight slots), then routed experts reuse slots + hb
    transpose_cvt_kernel<<<tg_gu, tb, 0, stream>>>(sw_gate, swgT, DM, HM);
    transpose_cvt_kernel<<<tg_gu, tb, 0, stream>>>(sw_up, swuT, DM, HM);
    transpose_cvt_kernel<<<tg_d, tb, 0, stream>>>(sw_down, swdT, HM, DM);
    gemm1_kernel<<<dim3(HM / 64, 64, 1), 256, 0, stream>>>(
        xb, wgT, wuT, swgT, swuT, segs, tok_of_row, hb, 7, 1);
    gemm2_kernel<<<dim3(DM / 128, 64, 1), 256, 0, stream>>>(
        hb, wdT, swdT, segs, yb, 7, 1);
    for (int e = 0; e < NE; e++) {
      transpose_cvt_kernel<<<tg_gu, tb, 0, stream>>>(w_gate + (size_t)e * WEXP, wgT, DM, HM);
      transpose_cvt_kernel<<<tg_gu, tb, 0, stream>>>(w_up + (size_t)e * WEXP, wuT, DM, HM);
      transpose_cvt_kernel<<<tg_d, tb, 0, stream>>>(w_down + (size_t)e * WEXP, wdT, HM, DM);
      gemm1_kernel<<<dim3(HM / 64, 64, 1), 256, 0, stream>>>(
          xb, wgT, wuT, swgT, swuT, segs, tok_of_row, hb, e, 1);
      gemm2_kernel<<<dim3(DM / 128, 64, 1), 256, 0, stream>>>(
          hb, wdT, swdT, segs, yb, e, 1);
    }
  }
  combine_kernel<<<NTOK, 256, 0, stream>>>(yb, row_of, t_w, out);
}